// Round 7
// baseline (506.460 us; speedup 1.0000x reference)
//
#include <hip/hip_runtime.h>
#include <hip/hip_fp16.h>
#include <math.h>

#define N_NODES 50000
#define E_EDGES 800000
#define E_TOT   850000   // E_EDGES + N_NODES self loops
#define F_IN    128
#define C1      256      // HEADS*HID
#define NCLS    47
#define H2S     48       // padded stride for H2 (47 -> 48)
#define W2PS    48       // padded class-stride for W2p (rows 192B, 16B-aligned)
#define NEG     0.2f
#define SCAN_B  196      // ceil(50000/256)

// ---------------- CSR build ----------------

__global__ void k_count(const int* __restrict__ ei, int* __restrict__ deg) {
    int i = blockIdx.x * 256 + threadIdx.x;
    if (i >= E_TOT) return;
    int dst = (i < E_EDGES) ? ei[E_EDGES + i] : (i - E_EDGES);
    atomicAdd(&deg[dst], 1);
}

// pass 1: per-block sums of deg
__global__ void k_scan_blk(const int* __restrict__ deg, int* __restrict__ blksum) {
    __shared__ int ws[4];
    int i = blockIdx.x * 256 + threadIdx.x;
    int v = (i < N_NODES) ? deg[i] : 0;
    int lane = threadIdx.x & 63, w = threadIdx.x >> 6;
    #pragma unroll
    for (int off = 32; off; off >>= 1) v += __shfl_xor(v, off);
    if (lane == 0) ws[w] = v;
    __syncthreads();
    if (threadIdx.x == 0) blksum[blockIdx.x] = ws[0] + ws[1] + ws[2] + ws[3];
}

// pass 2: single block exclusive-scans the SCAN_B block sums
__global__ void k_scan_top(const int* __restrict__ blksum, int* __restrict__ blkoff) {
    __shared__ int ws[4];
    int tid = threadIdx.x, lane = tid & 63, w = tid >> 6;
    int v = (tid < SCAN_B) ? blksum[tid] : 0;
    int sc = v;
    #pragma unroll
    for (int off = 1; off < 64; off <<= 1) {
        int t = __shfl_up(sc, off);
        if (lane >= off) sc += t;
    }
    if (lane == 63) ws[w] = sc;
    __syncthreads();
    if (tid == 0) { int a = 0; for (int t = 0; t < 4; t++) { int u = ws[t]; ws[t] = a; a += u; } }
    __syncthreads();
    if (tid < SCAN_B) blkoff[tid] = sc + ws[w] - v;   // exclusive
}

// pass 3: local scan + block offset -> row_ptr / cursor
__global__ void k_scan_fin(const int* __restrict__ deg, const int* __restrict__ blkoff,
                           int* __restrict__ row_ptr, int* __restrict__ cursor) {
    __shared__ int ws[4];
    int i = blockIdx.x * 256 + threadIdx.x;
    int v = (i < N_NODES) ? deg[i] : 0;
    int lane = threadIdx.x & 63, w = threadIdx.x >> 6;
    int sc = v;
    #pragma unroll
    for (int off = 1; off < 64; off <<= 1) {
        int t = __shfl_up(sc, off);
        if (lane >= off) sc += t;
    }
    if (lane == 63) ws[w] = sc;
    __syncthreads();
    if (threadIdx.x == 0) { int a = 0; for (int t = 0; t < 4; t++) { int u = ws[t]; ws[t] = a; a += u; } }
    __syncthreads();
    int incl = sc + ws[w] + blkoff[blockIdx.x];
    if (i < N_NODES) {
        row_ptr[i + 1] = incl;
        cursor[i]      = incl - v;
    }
    if (i == 0) row_ptr[0] = 0;
}

__global__ void k_scatter(const int* __restrict__ ei, int* __restrict__ cursor,
                          int* __restrict__ csr_src) {
    int i = blockIdx.x * 256 + threadIdx.x;
    if (i >= E_TOT) return;
    int src, dst;
    if (i < E_EDGES) { src = ei[i]; dst = ei[E_EDGES + i]; }
    else             { src = dst = i - E_EDGES; }
    int pos = atomicAdd(&cursor[dst], 1);
    csr_src[pos] = src;
}

// ---------------- W2 prep: pad [256][47] -> [256][48] (rows 192B, 16B-aligned) ----

__global__ void k_prepw2(const float* __restrict__ W2, float* __restrict__ W2p) {
    int i = blockIdx.x * 256 + threadIdx.x;
    if (i >= C1 * W2PS) return;
    int k = i / W2PS, c = i - k * W2PS;
    W2p[i] = (c < NCLS) ? W2[k * NCLS + c] : 0.f;
}

// ---------------- Layer 1: GEMM (x @ W1) + attention logits ----------------
// one wave per block, 16 rows; lane owns cols [lane*4, lane*4+4); head = lane>>4.
// H1 stored fp16 (gather payload only; logits from fp32 acc).

__global__ void __launch_bounds__(64)
k_gemm1(const float* __restrict__ x, const float* __restrict__ W1,
        const float* __restrict__ a_src1, const float* __restrict__ a_dst1,
        __half* __restrict__ H1h, float* __restrict__ al_s, float* __restrict__ al_d) {
    __shared__ float xs[16][F_IN];                      // 8 KB
    int n0 = blockIdx.x * 16;
    int lane = threadIdx.x;
    {
        const float4* xg = (const float4*)(x + (size_t)n0 * F_IN);
        float4* xs4 = (float4*)&xs[0][0];
        #pragma unroll
        for (int j = 0; j < 8; j++) xs4[lane + 64 * j] = xg[lane + 64 * j];
    }
    __syncthreads();
    int c4 = lane * 4;
    float acc[16][4] = {};
    for (int kg = 0; kg < F_IN; kg += 4) {
        float4 w0 = *(const float4*)(W1 + (size_t)(kg + 0) * C1 + c4);
        float4 w1 = *(const float4*)(W1 + (size_t)(kg + 1) * C1 + c4);
        float4 w2 = *(const float4*)(W1 + (size_t)(kg + 2) * C1 + c4);
        float4 w3 = *(const float4*)(W1 + (size_t)(kg + 3) * C1 + c4);
        #pragma unroll
        for (int r = 0; r < 16; r++) {
            float4 xv = *(const float4*)&xs[r][kg];     // wave-uniform broadcast
            acc[r][0] += xv.x * w0.x + xv.y * w1.x + xv.z * w2.x + xv.w * w3.x;
            acc[r][1] += xv.x * w0.y + xv.y * w1.y + xv.z * w2.y + xv.w * w3.y;
            acc[r][2] += xv.x * w0.z + xv.y * w1.z + xv.z * w2.z + xv.w * w3.z;
            acc[r][3] += xv.x * w0.w + xv.y * w1.w + xv.z * w2.w + xv.w * w3.w;
        }
    }
    int h = lane >> 4;
    int cc4 = (lane & 15) * 4;
    float4 as = *(const float4*)(a_src1 + h * 64 + cc4);
    float4 ad = *(const float4*)(a_dst1 + h * 64 + cc4);
    #pragma unroll
    for (int r = 0; r < 16; r++) {
        int n = n0 + r;
        ushort4 pk;
        pk.x = __half_as_ushort(__float2half_rn(acc[r][0]));
        pk.y = __half_as_ushort(__float2half_rn(acc[r][1]));
        pk.z = __half_as_ushort(__float2half_rn(acc[r][2]));
        pk.w = __half_as_ushort(__float2half_rn(acc[r][3]));
        *(ushort4*)(H1h + (size_t)n * C1 + c4) = pk;
        float vs = acc[r][0]*as.x + acc[r][1]*as.y + acc[r][2]*as.z + acc[r][3]*as.w;
        float vd = acc[r][0]*ad.x + acc[r][1]*ad.y + acc[r][2]*ad.z + acc[r][3]*ad.w;
        #pragma unroll
        for (int off = 8; off; off >>= 1) {
            vs += __shfl_xor(vs, off);
            vd += __shfl_xor(vd, off);
        }
        if ((lane & 15) == 0) {
            al_s[n * 4 + h] = vs;
            al_d[n * 4 + h] = vd;
        }
    }
}

// ---------------- Layer 1 aggregation: online softmax, one wave per node ----------------
// fp16 rows (512B), 4-edge unroll. Output HE now fp16 (feeds gemm2's row-stream).

__global__ void k_agg1(const __half* __restrict__ H1h, const float* __restrict__ al_s,
                       const float* __restrict__ al_d, const int* __restrict__ row_ptr,
                       const int* __restrict__ csr_src, const float* __restrict__ b1,
                       __half* __restrict__ HEh) {
    int n = blockIdx.x * 4 + (threadIdx.x >> 6);
    int lane = threadIdx.x & 63;
    int h = lane >> 4;
    int beg = row_ptr[n], end = row_ptr[n + 1];
    float ald = al_d[n * 4 + h];
    float m = -INFINITY, s = 0.f;
    float a0 = 0.f, a1 = 0.f, a2 = 0.f, a3 = 0.f;
    int j = beg;
    for (; j + 3 < end; j += 4) {
        int ss[4]; float ee[4]; ushort4 hh[4];
        #pragma unroll
        for (int t = 0; t < 4; t++) ss[t] = csr_src[j + t];
        #pragma unroll
        for (int t = 0; t < 4; t++) ee[t] = al_s[ss[t] * 4 + h];
        #pragma unroll
        for (int t = 0; t < 4; t++)
            hh[t] = *(const ushort4*)(H1h + (size_t)ss[t] * C1 + lane * 4);
        #pragma unroll
        for (int t = 0; t < 4; t++) {
            float e = ee[t] + ald;
            ee[t] = (e >= 0.f) ? e : NEG * e;
        }
        float nm = fmaxf(m, fmaxf(fmaxf(ee[0], ee[1]), fmaxf(ee[2], ee[3])));
        float f = __expf(m - nm);
        m = nm;
        float p[4];
        #pragma unroll
        for (int t = 0; t < 4; t++) p[t] = __expf(ee[t] - nm);
        s = s * f + p[0] + p[1] + p[2] + p[3];
        a0 *= f; a1 *= f; a2 *= f; a3 *= f;
        #pragma unroll
        for (int t = 0; t < 4; t++) {
            a0 += p[t] * __half2float(__ushort_as_half(hh[t].x));
            a1 += p[t] * __half2float(__ushort_as_half(hh[t].y));
            a2 += p[t] * __half2float(__ushort_as_half(hh[t].z));
            a3 += p[t] * __half2float(__ushort_as_half(hh[t].w));
        }
    }
    for (; j < end; j++) {
        int s0 = csr_src[j];
        float e = al_s[s0 * 4 + h] + ald;
        e = (e >= 0.f) ? e : NEG * e;
        ushort4 hv = *(const ushort4*)(H1h + (size_t)s0 * C1 + lane * 4);
        float nm = fmaxf(m, e);
        float f  = __expf(m - nm);
        float pr = __expf(e - nm);
        s  = s  * f + pr;
        a0 = a0 * f + pr * __half2float(__ushort_as_half(hv.x));
        a1 = a1 * f + pr * __half2float(__ushort_as_half(hv.y));
        a2 = a2 * f + pr * __half2float(__ushort_as_half(hv.z));
        a3 = a3 * f + pr * __half2float(__ushort_as_half(hv.w));
        m = nm;
    }
    float inv = 1.f / (s + 1e-16f);
    float4 bb = *(const float4*)(b1 + lane * 4);
    float o0 = a0 * inv + bb.x, o1 = a1 * inv + bb.y;
    float o2 = a2 * inv + bb.z, o3 = a3 * inv + bb.w;
    o0 = (o0 > 0.f) ? o0 : expm1f(o0);
    o1 = (o1 > 0.f) ? o1 : expm1f(o1);
    o2 = (o2 > 0.f) ? o2 : expm1f(o2);
    o3 = (o3 > 0.f) ? o3 : expm1f(o3);
    ushort4 pk;
    pk.x = __half_as_ushort(__float2half_rn(o0));
    pk.y = __half_as_ushort(__float2half_rn(o1));
    pk.z = __half_as_ushort(__float2half_rn(o2));
    pk.w = __half_as_ushort(__float2half_rn(o3));
    *(ushort4*)(HEh + (size_t)n * C1 + lane * 4) = pk;
}

// ---------------- Layer 2: GEMM (HE @ W2) + logits — lane-owns-row, zero LDS ----
// Each lane owns one output row: streams its 512B fp16 HE row in 8-half chunks
// (next-chunk prefetch), W2p read at wave-uniform addresses (L1/L2-resident),
// 48 class accumulators in registers with fully static indexing. No barriers,
// no shuffles, no idle lanes.

__global__ void __launch_bounds__(64)
k_gemm2(const __half* __restrict__ HEh, const float* __restrict__ W2p,
        const float* __restrict__ a_src2, const float* __restrict__ a_dst2,
        __half* __restrict__ H2h, float* __restrict__ al_s2, float* __restrict__ al_d2) {
    int row = blockIdx.x * 64 + threadIdx.x;
    int rr = (row < N_NODES) ? row : (N_NODES - 1);     // clamp loads; stores guarded
    const __half* hrow = HEh + (size_t)rr * C1;
    float acc[48];
    #pragma unroll
    for (int c = 0; c < 48; c++) acc[c] = 0.f;
    uint4 rb = *(const uint4*)(hrow);                   // chunk 0 (8 halves)
    #pragma unroll 1
    for (int k0 = 0; k0 < C1; k0 += 8) {
        uint4 rbn = *(const uint4*)(hrow + ((k0 + 8) & (C1 - 1)));  // prefetch (wraps, in-bounds)
        float rf[8];
        rf[0] = __half2float(__ushort_as_half((unsigned short)(rb.x & 0xffff)));
        rf[1] = __half2float(__ushort_as_half((unsigned short)(rb.x >> 16)));
        rf[2] = __half2float(__ushort_as_half((unsigned short)(rb.y & 0xffff)));
        rf[3] = __half2float(__ushort_as_half((unsigned short)(rb.y >> 16)));
        rf[4] = __half2float(__ushort_as_half((unsigned short)(rb.z & 0xffff)));
        rf[5] = __half2float(__ushort_as_half((unsigned short)(rb.z >> 16)));
        rf[6] = __half2float(__ushort_as_half((unsigned short)(rb.w & 0xffff)));
        rf[7] = __half2float(__ushort_as_half((unsigned short)(rb.w >> 16)));
        const float* wbase = W2p + (size_t)k0 * W2PS;
        #pragma unroll
        for (int kk = 0; kk < 8; kk++) {
            #pragma unroll
            for (int g = 0; g < 12; g++) {
                float4 wv = *(const float4*)(wbase + kk * W2PS + g * 4);  // uniform, aligned
                acc[g * 4 + 0] += rf[kk] * wv.x;
                acc[g * 4 + 1] += rf[kk] * wv.y;
                acc[g * 4 + 2] += rf[kk] * wv.z;
                acc[g * 4 + 3] += rf[kk] * wv.w;
            }
        }
        rb = rbn;
    }
    if (row < N_NODES) {
        unsigned int u[24];
        #pragma unroll
        for (int jj = 0; jj < 23; jj++) {
            unsigned int lo = __half_as_ushort(__float2half_rn(acc[2 * jj]));
            unsigned int hi = __half_as_ushort(__float2half_rn(acc[2 * jj + 1]));
            u[jj] = lo | (hi << 16);
        }
        u[23] = __half_as_ushort(__float2half_rn(acc[46]));
        __half* orow = H2h + (size_t)row * H2S;          // 96B rows, 16B-aligned
        *(uint4*)(orow + 0)  = make_uint4(u[0],  u[1],  u[2],  u[3]);
        *(uint4*)(orow + 8)  = make_uint4(u[4],  u[5],  u[6],  u[7]);
        *(uint4*)(orow + 16) = make_uint4(u[8],  u[9],  u[10], u[11]);
        *(uint4*)(orow + 24) = make_uint4(u[12], u[13], u[14], u[15]);
        *(uint4*)(orow + 32) = make_uint4(u[16], u[17], u[18], u[19]);
        *(uint2*)(orow + 40) = make_uint2(u[20], u[21]);
        *(unsigned int*)(orow + 44) = u[22];
        *(unsigned short*)(orow + 46) = (unsigned short)(u[23] & 0xffff);
        float vs = 0.f, vd = 0.f;
        #pragma unroll
        for (int c = 0; c < NCLS; c++) {
            vs += acc[c] * a_src2[c];
            vd += acc[c] * a_dst2[c];
        }
        al_s2[row] = vs;
        al_d2[row] = vd;
    }
}

// ---------------- Layer 2 aggregation + bias + log_softmax ----------------

__global__ void k_agg2(const __half* __restrict__ H2h, const float* __restrict__ al_s2,
                       const float* __restrict__ al_d2, const int* __restrict__ row_ptr,
                       const int* __restrict__ csr_src, const float* __restrict__ b2,
                       float* __restrict__ out) {
    int n = blockIdx.x * 4 + (threadIdx.x >> 6);
    if (n >= N_NODES) return;
    int lane = threadIdx.x & 63;
    int beg = row_ptr[n], end = row_ptr[n + 1];
    float ald = al_d2[n];
    float m = -INFINITY, s = 0.f, acc = 0.f;
    for (int j = beg; j < end; j++) {
        int src = csr_src[j];
        float e = al_s2[src] + ald;
        e = (e >= 0.f) ? e : NEG * e;
        float nm = fmaxf(m, e);
        float f  = __expf(m - nm);
        float pr = __expf(e - nm);
        s = s * f + pr;
        float hv = (lane < NCLS) ? __half2float(H2h[(size_t)src * H2S + lane]) : 0.f;
        acc = acc * f + pr * hv;
        m = nm;
    }
    float v = acc / (s + 1e-16f) + ((lane < NCLS) ? b2[lane] : -INFINITY);
    float mx = v;
    #pragma unroll
    for (int off = 32; off; off >>= 1) mx = fmaxf(mx, __shfl_xor(mx, off));
    float ex = __expf(v - mx);            // lanes >= 47 contribute 0
    float sum = ex;
    #pragma unroll
    for (int off = 32; off; off >>= 1) sum += __shfl_xor(sum, off);
    if (lane < NCLS) out[(size_t)n * NCLS + lane] = v - mx - logf(sum);
}

// ---------------- host ----------------

extern "C" void kernel_launch(void* const* d_in, const int* in_sizes, int n_in,
                              void* d_out, int out_size, void* d_ws, size_t ws_size,
                              hipStream_t stream) {
    const float* x      = (const float*)d_in[0];
    const int*   ei     = (const int*)  d_in[1];
    const float* W1     = (const float*)d_in[2];
    const float* a_src1 = (const float*)d_in[3];
    const float* a_dst1 = (const float*)d_in[4];
    const float* b1     = (const float*)d_in[5];
    const float* W2     = (const float*)d_in[6];
    const float* a_src2 = (const float*)d_in[7];
    const float* a_dst2 = (const float*)d_in[8];
    const float* b2     = (const float*)d_in[9];
    float* out = (float*)d_out;

    char* base = (char*)d_ws;
    size_t off = 0;
    auto alloc = [&](size_t bytes) -> void* {
        void* r = base + off;
        off += (bytes + 511) & ~size_t(511);
        return r;
    };
    __half* H1h   = (__half*)alloc((size_t)N_NODES * C1 * 2);
    __half* HEh   = (__half*)alloc((size_t)N_NODES * C1 * 2);
    __half* H2h   = (__half*)alloc((size_t)N_NODES * H2S * 2);
    float*  W2p   = (float*) alloc((size_t)C1 * W2PS * 4);
    float*  al_s1 = (float*) alloc((size_t)N_NODES * 4 * 4);
    float*  al_d1 = (float*) alloc((size_t)N_NODES * 4 * 4);
    float*  al_s2 = (float*) alloc((size_t)N_NODES * 4);
    float*  al_d2 = (float*) alloc((size_t)N_NODES * 4);
    int*    deg   = (int*)   alloc((size_t)N_NODES * 4);
    int*    rowp  = (int*)   alloc((size_t)(N_NODES + 1) * 4);
    int*    cursor= (int*)   alloc((size_t)N_NODES * 4);
    int*    blks  = (int*)   alloc((size_t)SCAN_B * 4);
    int*    blko  = (int*)   alloc((size_t)SCAN_B * 4);
    int*    csrs  = (int*)   alloc((size_t)E_TOT * 4);

    hipMemsetAsync(deg, 0, (size_t)N_NODES * 4, stream);

    int eb = (E_TOT + 255) / 256;
    k_count   <<<eb, 256, 0, stream>>>(ei, deg);
    k_scan_blk<<<SCAN_B, 256, 0, stream>>>(deg, blks);
    k_scan_top<<<1, 256, 0, stream>>>(blks, blko);
    k_scan_fin<<<SCAN_B, 256, 0, stream>>>(deg, blko, rowp, cursor);
    k_scatter <<<eb, 256, 0, stream>>>(ei, cursor, csrs);
    k_prepw2  <<<(C1 * W2PS + 255) / 256, 256, 0, stream>>>(W2, W2p);

    k_gemm1<<<N_NODES / 16, 64, 0, stream>>>(x, W1, a_src1, a_dst1, H1h, al_s1, al_d1);
    k_agg1 <<<(N_NODES + 3) / 4, 256, 0, stream>>>(H1h, al_s1, al_d1, rowp, csrs, b1, HEh);
    k_gemm2<<<(N_NODES + 63) / 64, 64, 0, stream>>>(HEh, W2p, a_src2, a_dst2, H2h, al_s2, al_d2);
    k_agg2 <<<(N_NODES + 3) / 4, 256, 0, stream>>>(H2h, al_s2, al_d2, rowp, csrs, b2, out);
}

// Round 9
// 415.987 us; speedup vs baseline: 1.2175x; 1.2175x over previous
//
#include <hip/hip_runtime.h>
#include <hip/hip_fp16.h>
#include <math.h>

#define N_NODES 50000
#define E_EDGES 800000
#define E_TOT   850000   // E_EDGES + N_NODES self loops
#define F_IN    128
#define C1      256      // HEADS*HID
#define NCLS    47
#define H2S     48       // padded stride for H2 (47 -> 48)
#define NEG     0.2f
#define SCAN_B  196      // ceil(50000/256)

typedef _Float16 f16x8 __attribute__((ext_vector_type(8)));
typedef float    f32x4 __attribute__((ext_vector_type(4)));

// ---------------- CSR build ----------------

__global__ void k_count(const int* __restrict__ ei, int* __restrict__ deg) {
    int i = blockIdx.x * 256 + threadIdx.x;
    if (i >= E_TOT) return;
    int dst = (i < E_EDGES) ? ei[E_EDGES + i] : (i - E_EDGES);
    atomicAdd(&deg[dst], 1);
}

// pass 1: per-block sums of deg
__global__ void k_scan_blk(const int* __restrict__ deg, int* __restrict__ blksum) {
    __shared__ int ws[4];
    int i = blockIdx.x * 256 + threadIdx.x;
    int v = (i < N_NODES) ? deg[i] : 0;
    int lane = threadIdx.x & 63, w = threadIdx.x >> 6;
    #pragma unroll
    for (int off = 32; off; off >>= 1) v += __shfl_xor(v, off);
    if (lane == 0) ws[w] = v;
    __syncthreads();
    if (threadIdx.x == 0) blksum[blockIdx.x] = ws[0] + ws[1] + ws[2] + ws[3];
}

// pass 2: single block exclusive-scans the SCAN_B block sums
__global__ void k_scan_top(const int* __restrict__ blksum, int* __restrict__ blkoff) {
    __shared__ int ws[4];
    int tid = threadIdx.x, lane = tid & 63, w = tid >> 6;
    int v = (tid < SCAN_B) ? blksum[tid] : 0;
    int sc = v;
    #pragma unroll
    for (int off = 1; off < 64; off <<= 1) {
        int t = __shfl_up(sc, off);
        if (lane >= off) sc += t;
    }
    if (lane == 63) ws[w] = sc;
    __syncthreads();
    if (tid == 0) { int a = 0; for (int t = 0; t < 4; t++) { int u = ws[t]; ws[t] = a; a += u; } }
    __syncthreads();
    if (tid < SCAN_B) blkoff[tid] = sc + ws[w] - v;   // exclusive
}

// pass 3: local scan + block offset -> row_ptr / cursor
__global__ void k_scan_fin(const int* __restrict__ deg, const int* __restrict__ blkoff,
                           int* __restrict__ row_ptr, int* __restrict__ cursor) {
    __shared__ int ws[4];
    int i = blockIdx.x * 256 + threadIdx.x;
    int v = (i < N_NODES) ? deg[i] : 0;
    int lane = threadIdx.x & 63, w = threadIdx.x >> 6;
    int sc = v;
    #pragma unroll
    for (int off = 1; off < 64; off <<= 1) {
        int t = __shfl_up(sc, off);
        if (lane >= off) sc += t;
    }
    if (lane == 63) ws[w] = sc;
    __syncthreads();
    if (threadIdx.x == 0) { int a = 0; for (int t = 0; t < 4; t++) { int u = ws[t]; ws[t] = a; a += u; } }
    __syncthreads();
    int incl = sc + ws[w] + blkoff[blockIdx.x];
    if (i < N_NODES) {
        row_ptr[i + 1] = incl;
        cursor[i]      = incl - v;
    }
    if (i == 0) row_ptr[0] = 0;
}

__global__ void k_scatter(const int* __restrict__ ei, int* __restrict__ cursor,
                          int* __restrict__ csr_src) {
    int i = blockIdx.x * 256 + threadIdx.x;
    if (i >= E_TOT) return;
    int src, dst;
    if (i < E_EDGES) { src = ei[i]; dst = ei[E_EDGES + i]; }
    else             { src = dst = i - E_EDGES; }
    int pos = atomicAdd(&cursor[dst], 1);
    csr_src[pos] = src;
}

// ---------------- W2 prep: pack into MFMA B-fragments (fp16) ----------------
// W2f[(f*8+ks)*64 + lane] = 8 halves: W2[k = ks*32 + (lane>>4)*8 + j][c = f*16 + (lane&15)],
// zero-padded for c >= 47. Same k-mapping as the A-frag load in k_gemm2, so any
// hardware k-order bijection cancels.

__global__ void k_prepw2f(const float* __restrict__ W2, uint4* __restrict__ W2f) {
    int t = blockIdx.x * 256 + threadIdx.x;
    if (t >= 1536) return;
    int f = t >> 9, ks = (t >> 6) & 7, lane = t & 63;
    int c  = f * 16 + (lane & 15);
    int kb = ks * 32 + ((lane >> 4) << 3);
    unsigned short h[8];
    #pragma unroll
    for (int j = 0; j < 8; j++) {
        float v = (c < NCLS) ? W2[(size_t)(kb + j) * NCLS + c] : 0.f;
        h[j] = __half_as_ushort(__float2half_rn(v));
    }
    W2f[t] = make_uint4((unsigned)h[0] | ((unsigned)h[1] << 16),
                        (unsigned)h[2] | ((unsigned)h[3] << 16),
                        (unsigned)h[4] | ((unsigned)h[5] << 16),
                        (unsigned)h[6] | ((unsigned)h[7] << 16));
}

// ---------------- Layer 1: GEMM (x @ W1) + attention logits ----------------
// one wave per block, 16 rows; lane owns cols [lane*4, lane*4+4); head = lane>>4.
// H1 stored fp16 (gather payload only; logits from fp32 acc).

__global__ void __launch_bounds__(64)
k_gemm1(const float* __restrict__ x, const float* __restrict__ W1,
        const float* __restrict__ a_src1, const float* __restrict__ a_dst1,
        __half* __restrict__ H1h, float* __restrict__ al_s, float* __restrict__ al_d) {
    __shared__ float xs[16][F_IN];                      // 8 KB
    int n0 = blockIdx.x * 16;
    int lane = threadIdx.x;
    {
        const float4* xg = (const float4*)(x + (size_t)n0 * F_IN);
        float4* xs4 = (float4*)&xs[0][0];
        #pragma unroll
        for (int j = 0; j < 8; j++) xs4[lane + 64 * j] = xg[lane + 64 * j];
    }
    __syncthreads();
    int c4 = lane * 4;
    float acc[16][4] = {};
    for (int kg = 0; kg < F_IN; kg += 4) {
        float4 w0 = *(const float4*)(W1 + (size_t)(kg + 0) * C1 + c4);
        float4 w1 = *(const float4*)(W1 + (size_t)(kg + 1) * C1 + c4);
        float4 w2 = *(const float4*)(W1 + (size_t)(kg + 2) * C1 + c4);
        float4 w3 = *(const float4*)(W1 + (size_t)(kg + 3) * C1 + c4);
        #pragma unroll
        for (int r = 0; r < 16; r++) {
            float4 xv = *(const float4*)&xs[r][kg];     // wave-uniform broadcast
            acc[r][0] += xv.x * w0.x + xv.y * w1.x + xv.z * w2.x + xv.w * w3.x;
            acc[r][1] += xv.x * w0.y + xv.y * w1.y + xv.z * w2.y + xv.w * w3.y;
            acc[r][2] += xv.x * w0.z + xv.y * w1.z + xv.z * w2.z + xv.w * w3.z;
            acc[r][3] += xv.x * w0.w + xv.y * w1.w + xv.z * w2.w + xv.w * w3.w;
        }
    }
    int h = lane >> 4;
    int cc4 = (lane & 15) * 4;
    float4 as = *(const float4*)(a_src1 + h * 64 + cc4);
    float4 ad = *(const float4*)(a_dst1 + h * 64 + cc4);
    #pragma unroll
    for (int r = 0; r < 16; r++) {
        int n = n0 + r;
        ushort4 pk;
        pk.x = __half_as_ushort(__float2half_rn(acc[r][0]));
        pk.y = __half_as_ushort(__float2half_rn(acc[r][1]));
        pk.z = __half_as_ushort(__float2half_rn(acc[r][2]));
        pk.w = __half_as_ushort(__float2half_rn(acc[r][3]));
        *(ushort4*)(H1h + (size_t)n * C1 + c4) = pk;
        float vs = acc[r][0]*as.x + acc[r][1]*as.y + acc[r][2]*as.z + acc[r][3]*as.w;
        float vd = acc[r][0]*ad.x + acc[r][1]*ad.y + acc[r][2]*ad.z + acc[r][3]*ad.w;
        #pragma unroll
        for (int off = 8; off; off >>= 1) {
            vs += __shfl_xor(vs, off);
            vd += __shfl_xor(vd, off);
        }
        if ((lane & 15) == 0) {
            al_s[n * 4 + h] = vs;
            al_d[n * 4 + h] = vd;
        }
    }
}

// ---------------- Layer 1 aggregation: online softmax, one wave per node ----------------
// fp16 rows (512B), 4-edge unroll. Output HE fp16 (feeds gemm2's MFMA A-operand).

__global__ void k_agg1(const __half* __restrict__ H1h, const float* __restrict__ al_s,
                       const float* __restrict__ al_d, const int* __restrict__ row_ptr,
                       const int* __restrict__ csr_src, const float* __restrict__ b1,
                       __half* __restrict__ HEh) {
    int n = blockIdx.x * 4 + (threadIdx.x >> 6);
    int lane = threadIdx.x & 63;
    int h = lane >> 4;
    int beg = row_ptr[n], end = row_ptr[n + 1];
    float ald = al_d[n * 4 + h];
    float m = -INFINITY, s = 0.f;
    float a0 = 0.f, a1 = 0.f, a2 = 0.f, a3 = 0.f;
    int j = beg;
    for (; j + 3 < end; j += 4) {
        int ss[4]; float ee[4]; ushort4 hh[4];
        #pragma unroll
        for (int t = 0; t < 4; t++) ss[t] = csr_src[j + t];
        #pragma unroll
        for (int t = 0; t < 4; t++) ee[t] = al_s[ss[t] * 4 + h];
        #pragma unroll
        for (int t = 0; t < 4; t++)
            hh[t] = *(const ushort4*)(H1h + (size_t)ss[t] * C1 + lane * 4);
        #pragma unroll
        for (int t = 0; t < 4; t++) {
            float e = ee[t] + ald;
            ee[t] = (e >= 0.f) ? e : NEG * e;
        }
        float nm = fmaxf(m, fmaxf(fmaxf(ee[0], ee[1]), fmaxf(ee[2], ee[3])));
        float f = __expf(m - nm);
        m = nm;
        float p[4];
        #pragma unroll
        for (int t = 0; t < 4; t++) p[t] = __expf(ee[t] - nm);
        s = s * f + p[0] + p[1] + p[2] + p[3];
        a0 *= f; a1 *= f; a2 *= f; a3 *= f;
        #pragma unroll
        for (int t = 0; t < 4; t++) {
            a0 += p[t] * __half2float(__ushort_as_half(hh[t].x));
            a1 += p[t] * __half2float(__ushort_as_half(hh[t].y));
            a2 += p[t] * __half2float(__ushort_as_half(hh[t].z));
            a3 += p[t] * __half2float(__ushort_as_half(hh[t].w));
        }
    }
    for (; j < end; j++) {
        int s0 = csr_src[j];
        float e = al_s[s0 * 4 + h] + ald;
        e = (e >= 0.f) ? e : NEG * e;
        ushort4 hv = *(const ushort4*)(H1h + (size_t)s0 * C1 + lane * 4);
        float nm = fmaxf(m, e);
        float f  = __expf(m - nm);
        float pr = __expf(e - nm);
        s  = s  * f + pr;
        a0 = a0 * f + pr * __half2float(__ushort_as_half(hv.x));
        a1 = a1 * f + pr * __half2float(__ushort_as_half(hv.y));
        a2 = a2 * f + pr * __half2float(__ushort_as_half(hv.z));
        a3 = a3 * f + pr * __half2float(__ushort_as_half(hv.w));
        m = nm;
    }
    float inv = 1.f / (s + 1e-16f);
    float4 bb = *(const float4*)(b1 + lane * 4);
    float o0 = a0 * inv + bb.x, o1 = a1 * inv + bb.y;
    float o2 = a2 * inv + bb.z, o3 = a3 * inv + bb.w;
    o0 = (o0 > 0.f) ? o0 : expm1f(o0);
    o1 = (o1 > 0.f) ? o1 : expm1f(o1);
    o2 = (o2 > 0.f) ? o2 : expm1f(o2);
    o3 = (o3 > 0.f) ? o3 : expm1f(o3);
    ushort4 pk;
    pk.x = __half_as_ushort(__float2half_rn(o0));
    pk.y = __half_as_ushort(__float2half_rn(o1));
    pk.z = __half_as_ushort(__float2half_rn(o2));
    pk.w = __half_as_ushort(__float2half_rn(o3));
    *(ushort4*)(HEh + (size_t)n * C1 + lane * 4) = pk;
}

// ---------------- Layer 2: GEMM (HE @ W2) via MFMA + logits ----------------
// One wave per 16 output rows (3125 waves, ~3/SIMD). 24 mfma_f32_16x16x32_f16
// per wave. A-frag: lane holds HEh[n0+(lane&15)][ks*32+(lane>>4)*8 + 0..7].
// B-frags prepacked by k_prepw2f with the same k-mapping. D (m89-verified):
// col = lane&15, row = (lane>>4)*4 + reg.

__global__ void __launch_bounds__(64)
k_gemm2(const __half* __restrict__ HEh, const uint4* __restrict__ W2f,
        const float* __restrict__ a_src2, const float* __restrict__ a_dst2,
        __half* __restrict__ H2h, float* __restrict__ al_s2, float* __restrict__ al_d2) {
    int lane = threadIdx.x;
    int n0 = blockIdx.x * 16;
    const __half* aptr = HEh + (size_t)(n0 + (lane & 15)) * C1 + ((lane >> 4) << 3);
    const f16x8* bptr = (const f16x8*)W2f;
    f32x4 acc0 = {0.f, 0.f, 0.f, 0.f};
    f32x4 acc1 = {0.f, 0.f, 0.f, 0.f};
    f32x4 acc2 = {0.f, 0.f, 0.f, 0.f};
    #pragma unroll
    for (int ks = 0; ks < 8; ks++) {
        f16x8 a  = *(const f16x8*)(aptr + ks * 32);
        f16x8 b0 = bptr[(0 * 8 + ks) * 64 + lane];
        f16x8 b1 = bptr[(1 * 8 + ks) * 64 + lane];
        f16x8 b2 = bptr[(2 * 8 + ks) * 64 + lane];
        acc0 = __builtin_amdgcn_mfma_f32_16x16x32_f16(a, b0, acc0, 0, 0, 0);
        acc1 = __builtin_amdgcn_mfma_f32_16x16x32_f16(a, b1, acc1, 0, 0, 0);
        acc2 = __builtin_amdgcn_mfma_f32_16x16x32_f16(a, b2, acc2, 0, 0, 0);
    }
    int col = lane & 15;
    int g4  = (lane >> 4) * 4;
    float as[3], ad[3];
    #pragma unroll
    for (int f = 0; f < 3; f++) {
        int c = f * 16 + col;
        as[f] = (c < NCLS) ? a_src2[c] : 0.f;
        ad[f] = (c < NCLS) ? a_dst2[c] : 0.f;
    }
    #pragma unroll
    for (int reg = 0; reg < 4; reg++) {
        int n = n0 + g4 + reg;
        float v0 = acc0[reg], v1 = acc1[reg], v2 = acc2[reg];
        __half* orow = H2h + (size_t)n * H2S;
        orow[col]      = __float2half_rn(v0);
        orow[16 + col] = __float2half_rn(v1);
        orow[32 + col] = __float2half_rn(v2);   // col 47 = pad (zero from padded W2f)
        float vs = v0 * as[0] + v1 * as[1] + v2 * as[2];
        float vd = v0 * ad[0] + v1 * ad[1] + v2 * ad[2];
        #pragma unroll
        for (int off = 8; off; off >>= 1) {     // reduce across the 16-lane row group
            vs += __shfl_xor(vs, off);
            vd += __shfl_xor(vd, off);
        }
        if (col == 0) { al_s2[n] = vs; al_d2[n] = vd; }
    }
}

// ---------------- Layer 2 aggregation + bias + log_softmax ----------------

__global__ void k_agg2(const __half* __restrict__ H2h, const float* __restrict__ al_s2,
                       const float* __restrict__ al_d2, const int* __restrict__ row_ptr,
                       const int* __restrict__ csr_src, const float* __restrict__ b2,
                       float* __restrict__ out) {
    int n = blockIdx.x * 4 + (threadIdx.x >> 6);
    if (n >= N_NODES) return;
    int lane = threadIdx.x & 63;
    int beg = row_ptr[n], end = row_ptr[n + 1];
    float ald = al_d2[n];
    float m = -INFINITY, s = 0.f, acc = 0.f;
    for (int j = beg; j < end; j++) {
        int src = csr_src[j];
        float e = al_s2[src] + ald;
        e = (e >= 0.f) ? e : NEG * e;
        float nm = fmaxf(m, e);
        float f  = __expf(m - nm);
        float pr = __expf(e - nm);
        s = s * f + pr;
        float hv = (lane < NCLS) ? __half2float(H2h[(size_t)src * H2S + lane]) : 0.f;
        acc = acc * f + pr * hv;
        m = nm;
    }
    float v = acc / (s + 1e-16f) + ((lane < NCLS) ? b2[lane] : -INFINITY);
    float mx = v;
    #pragma unroll
    for (int off = 32; off; off >>= 1) mx = fmaxf(mx, __shfl_xor(mx, off));
    float ex = __expf(v - mx);            // lanes >= 47 contribute 0
    float sum = ex;
    #pragma unroll
    for (int off = 32; off; off >>= 1) sum += __shfl_xor(sum, off);
    if (lane < NCLS) out[(size_t)n * NCLS + lane] = v - mx - logf(sum);
}

// ---------------- host ----------------

extern "C" void kernel_launch(void* const* d_in, const int* in_sizes, int n_in,
                              void* d_out, int out_size, void* d_ws, size_t ws_size,
                              hipStream_t stream) {
    const float* x      = (const float*)d_in[0];
    const int*   ei     = (const int*)  d_in[1];
    const float* W1     = (const float*)d_in[2];
    const float* a_src1 = (const float*)d_in[3];
    const float* a_dst1 = (const float*)d_in[4];
    const float* b1     = (const float*)d_in[5];
    const float* W2     = (const float*)d_in[6];
    const float* a_src2 = (const float*)d_in[7];
    const float* a_dst2 = (const float*)d_in[8];
    const float* b2     = (const float*)d_in[9];
    float* out = (float*)d_out;

    char* base = (char*)d_ws;
    size_t off = 0;
    auto alloc = [&](size_t bytes) -> void* {
        void* r = base + off;
        off += (bytes + 511) & ~size_t(511);
        return r;
    };
    __half* H1h   = (__half*)alloc((size_t)N_NODES * C1 * 2);
    __half* HEh   = (__half*)alloc((size_t)N_NODES * C1 * 2);
    __half* H2h   = (__half*)alloc((size_t)N_NODES * H2S * 2);
    uint4*  W2f   = (uint4*) alloc((size_t)1536 * 16);
    float*  al_s1 = (float*) alloc((size_t)N_NODES * 4 * 4);
    float*  al_d1 = (float*) alloc((size_t)N_NODES * 4 * 4);
    float*  al_s2 = (float*) alloc((size_t)N_NODES * 4);
    float*  al_d2 = (float*) alloc((size_t)N_NODES * 4);
    int*    deg   = (int*)   alloc((size_t)N_NODES * 4);
    int*    rowp  = (int*)   alloc((size_t)(N_NODES + 1) * 4);
    int*    cursor= (int*)   alloc((size_t)N_NODES * 4);
    int*    blks  = (int*)   alloc((size_t)SCAN_B * 4);
    int*    blko  = (int*)   alloc((size_t)SCAN_B * 4);
    int*    csrs  = (int*)   alloc((size_t)E_TOT * 4);

    hipMemsetAsync(deg, 0, (size_t)N_NODES * 4, stream);

    int eb = (E_TOT + 255) / 256;
    k_count   <<<eb, 256, 0, stream>>>(ei, deg);
    k_scan_blk<<<SCAN_B, 256, 0, stream>>>(deg, blks);
    k_scan_top<<<1, 256, 0, stream>>>(blks, blko);
    k_scan_fin<<<SCAN_B, 256, 0, stream>>>(deg, blko, rowp, cursor);
    k_scatter <<<eb, 256, 0, stream>>>(ei, cursor, csrs);
    k_prepw2f <<<6, 256, 0, stream>>>(W2, W2f);

    k_gemm1<<<N_NODES / 16, 64, 0, stream>>>(x, W1, a_src1, a_dst1, H1h, al_s1, al_d1);
    k_agg1 <<<(N_NODES + 3) / 4, 256, 0, stream>>>(H1h, al_s1, al_d1, rowp, csrs, b1, HEh);
    k_gemm2<<<N_NODES / 16, 64, 0, stream>>>(HEh, W2f, a_src2, a_dst2, H2h, al_s2, al_d2);
    k_agg2 <<<(N_NODES + 3) / 4, 256, 0, stream>>>(H2h, al_s2, al_d2, rowp, csrs, b2, out);
}

// Round 11
// 390.772 us; speedup vs baseline: 1.2960x; 1.0645x over previous
//
#include <hip/hip_runtime.h>
#include <hip/hip_fp16.h>
#include <math.h>

#define N_NODES 50000
#define E_EDGES 800000
#define E_TOT   850000   // E_EDGES + N_NODES self loops
#define F_IN    128
#define C1      256      // HEADS*HID
#define NCLS    47
#define H2S     48       // padded stride for H2 (47 -> 48)
#define NEG     0.2f
#define SCAN_B  196      // ceil(50000/256)

typedef _Float16 f16x8 __attribute__((ext_vector_type(8)));
typedef float    f32x4 __attribute__((ext_vector_type(4)));

// ---------------- CSR build ----------------

__global__ void k_count(const int* __restrict__ ei, int* __restrict__ deg) {
    int i = blockIdx.x * 256 + threadIdx.x;
    if (i >= E_TOT) return;
    int dst = (i < E_EDGES) ? ei[E_EDGES + i] : (i - E_EDGES);
    atomicAdd(&deg[dst], 1);
}

// pass 1: per-block sums of deg
__global__ void k_scan_blk(const int* __restrict__ deg, int* __restrict__ blksum) {
    __shared__ int ws[4];
    int i = blockIdx.x * 256 + threadIdx.x;
    int v = (i < N_NODES) ? deg[i] : 0;
    int lane = threadIdx.x & 63, w = threadIdx.x >> 6;
    #pragma unroll
    for (int off = 32; off; off >>= 1) v += __shfl_xor(v, off);
    if (lane == 0) ws[w] = v;
    __syncthreads();
    if (threadIdx.x == 0) blksum[blockIdx.x] = ws[0] + ws[1] + ws[2] + ws[3];
}

// pass 2: single block exclusive-scans the SCAN_B block sums
__global__ void k_scan_top(const int* __restrict__ blksum, int* __restrict__ blkoff) {
    __shared__ int ws[4];
    int tid = threadIdx.x, lane = tid & 63, w = tid >> 6;
    int v = (tid < SCAN_B) ? blksum[tid] : 0;
    int sc = v;
    #pragma unroll
    for (int off = 1; off < 64; off <<= 1) {
        int t = __shfl_up(sc, off);
        if (lane >= off) sc += t;
    }
    if (lane == 63) ws[w] = sc;
    __syncthreads();
    if (tid == 0) { int a = 0; for (int t = 0; t < 4; t++) { int u = ws[t]; ws[t] = a; a += u; } }
    __syncthreads();
    if (tid < SCAN_B) blkoff[tid] = sc + ws[w] - v;   // exclusive
}

// pass 3: local scan + block offset -> row_ptr / cursor
__global__ void k_scan_fin(const int* __restrict__ deg, const int* __restrict__ blkoff,
                           int* __restrict__ row_ptr, int* __restrict__ cursor) {
    __shared__ int ws[4];
    int i = blockIdx.x * 256 + threadIdx.x;
    int v = (i < N_NODES) ? deg[i] : 0;
    int lane = threadIdx.x & 63, w = threadIdx.x >> 6;
    int sc = v;
    #pragma unroll
    for (int off = 1; off < 64; off <<= 1) {
        int t = __shfl_up(sc, off);
        if (lane >= off) sc += t;
    }
    if (lane == 63) ws[w] = sc;
    __syncthreads();
    if (threadIdx.x == 0) { int a = 0; for (int t = 0; t < 4; t++) { int u = ws[t]; ws[t] = a; a += u; } }
    __syncthreads();
    int incl = sc + ws[w] + blkoff[blockIdx.x];
    if (i < N_NODES) {
        row_ptr[i + 1] = incl;
        cursor[i]      = incl - v;
    }
    if (i == 0) row_ptr[0] = 0;
}

__global__ void k_scatter(const int* __restrict__ ei, int* __restrict__ cursor,
                          int* __restrict__ csr_src) {
    int i = blockIdx.x * 256 + threadIdx.x;
    if (i >= E_TOT) return;
    int src, dst;
    if (i < E_EDGES) { src = ei[i]; dst = ei[E_EDGES + i]; }
    else             { src = dst = i - E_EDGES; }
    int pos = atomicAdd(&cursor[dst], 1);
    csr_src[pos] = src;
}

// ---------------- W2 prep: pack into MFMA B-fragments (fp16) ----------------
// W2f[(f*8+ks)*64 + lane] = 8 halves: W2[k = ks*32 + (lane>>4)*8 + j][c = f*16 + (lane&15)],
// zero-padded for c >= 47. Same k-mapping as the A-frag load in k_gemm2, so any
// hardware k-order bijection cancels.

__global__ void k_prepw2f(const float* __restrict__ W2, uint4* __restrict__ W2f) {
    int t = blockIdx.x * 256 + threadIdx.x;
    if (t >= 1536) return;
    int f = t >> 9, ks = (t >> 6) & 7, lane = t & 63;
    int c  = f * 16 + (lane & 15);
    int kb = ks * 32 + ((lane >> 4) << 3);
    unsigned short h[8];
    #pragma unroll
    for (int j = 0; j < 8; j++) {
        float v = (c < NCLS) ? W2[(size_t)(kb + j) * NCLS + c] : 0.f;
        h[j] = __half_as_ushort(__float2half_rn(v));
    }
    W2f[t] = make_uint4((unsigned)h[0] | ((unsigned)h[1] << 16),
                        (unsigned)h[2] | ((unsigned)h[3] << 16),
                        (unsigned)h[4] | ((unsigned)h[5] << 16),
                        (unsigned)h[6] | ((unsigned)h[7] << 16));
}

// ---------------- Layer 1: GEMM (x @ W1) + attention logits ----------------
// one wave per block, 16 rows; lane owns cols [lane*4, lane*4+4); head = lane>>4.
// H1 stored fp16 (gather payload only; logits from fp32 acc).

__global__ void __launch_bounds__(64)
k_gemm1(const float* __restrict__ x, const float* __restrict__ W1,
        const float* __restrict__ a_src1, const float* __restrict__ a_dst1,
        __half* __restrict__ H1h, float* __restrict__ al_s, float* __restrict__ al_d) {
    __shared__ float xs[16][F_IN];                      // 8 KB
    int n0 = blockIdx.x * 16;
    int lane = threadIdx.x;
    {
        const float4* xg = (const float4*)(x + (size_t)n0 * F_IN);
        float4* xs4 = (float4*)&xs[0][0];
        #pragma unroll
        for (int j = 0; j < 8; j++) xs4[lane + 64 * j] = xg[lane + 64 * j];
    }
    __syncthreads();
    int c4 = lane * 4;
    float acc[16][4] = {};
    for (int kg = 0; kg < F_IN; kg += 4) {
        float4 w0 = *(const float4*)(W1 + (size_t)(kg + 0) * C1 + c4);
        float4 w1 = *(const float4*)(W1 + (size_t)(kg + 1) * C1 + c4);
        float4 w2 = *(const float4*)(W1 + (size_t)(kg + 2) * C1 + c4);
        float4 w3 = *(const float4*)(W1 + (size_t)(kg + 3) * C1 + c4);
        #pragma unroll
        for (int r = 0; r < 16; r++) {
            float4 xv = *(const float4*)&xs[r][kg];     // wave-uniform broadcast
            acc[r][0] += xv.x * w0.x + xv.y * w1.x + xv.z * w2.x + xv.w * w3.x;
            acc[r][1] += xv.x * w0.y + xv.y * w1.y + xv.z * w2.y + xv.w * w3.y;
            acc[r][2] += xv.x * w0.z + xv.y * w1.z + xv.z * w2.z + xv.w * w3.z;
            acc[r][3] += xv.x * w0.w + xv.y * w1.w + xv.z * w2.w + xv.w * w3.w;
        }
    }
    int h = lane >> 4;
    int cc4 = (lane & 15) * 4;
    float4 as = *(const float4*)(a_src1 + h * 64 + cc4);
    float4 ad = *(const float4*)(a_dst1 + h * 64 + cc4);
    #pragma unroll
    for (int r = 0; r < 16; r++) {
        int n = n0 + r;
        ushort4 pk;
        pk.x = __half_as_ushort(__float2half_rn(acc[r][0]));
        pk.y = __half_as_ushort(__float2half_rn(acc[r][1]));
        pk.z = __half_as_ushort(__float2half_rn(acc[r][2]));
        pk.w = __half_as_ushort(__float2half_rn(acc[r][3]));
        *(ushort4*)(H1h + (size_t)n * C1 + c4) = pk;
        float vs = acc[r][0]*as.x + acc[r][1]*as.y + acc[r][2]*as.z + acc[r][3]*as.w;
        float vd = acc[r][0]*ad.x + acc[r][1]*ad.y + acc[r][2]*ad.z + acc[r][3]*ad.w;
        #pragma unroll
        for (int off = 8; off; off >>= 1) {
            vs += __shfl_xor(vs, off);
            vd += __shfl_xor(vd, off);
        }
        if ((lane & 15) == 0) {
            al_s[n * 4 + h] = vs;
            al_d[n * 4 + h] = vd;
        }
    }
}

// ---------------- Layer 1 aggregation: online softmax, one wave per node ----------------
// fp16 rows (512B), 4-edge unroll. Output HE fp16 (feeds gemm2's MFMA A-operand).

__global__ void k_agg1(const __half* __restrict__ H1h, const float* __restrict__ al_s,
                       const float* __restrict__ al_d, const int* __restrict__ row_ptr,
                       const int* __restrict__ csr_src, const float* __restrict__ b1,
                       __half* __restrict__ HEh) {
    int n = blockIdx.x * 4 + (threadIdx.x >> 6);
    int lane = threadIdx.x & 63;
    int h = lane >> 4;
    int beg = row_ptr[n], end = row_ptr[n + 1];
    float ald = al_d[n * 4 + h];
    float m = -INFINITY, s = 0.f;
    float a0 = 0.f, a1 = 0.f, a2 = 0.f, a3 = 0.f;
    int j = beg;
    for (; j + 3 < end; j += 4) {
        int ss[4]; float ee[4]; ushort4 hh[4];
        #pragma unroll
        for (int t = 0; t < 4; t++) ss[t] = csr_src[j + t];
        #pragma unroll
        for (int t = 0; t < 4; t++) ee[t] = al_s[ss[t] * 4 + h];
        #pragma unroll
        for (int t = 0; t < 4; t++)
            hh[t] = *(const ushort4*)(H1h + (size_t)ss[t] * C1 + lane * 4);
        #pragma unroll
        for (int t = 0; t < 4; t++) {
            float e = ee[t] + ald;
            ee[t] = (e >= 0.f) ? e : NEG * e;
        }
        float nm = fmaxf(m, fmaxf(fmaxf(ee[0], ee[1]), fmaxf(ee[2], ee[3])));
        float f = __expf(m - nm);
        m = nm;
        float p[4];
        #pragma unroll
        for (int t = 0; t < 4; t++) p[t] = __expf(ee[t] - nm);
        s = s * f + p[0] + p[1] + p[2] + p[3];
        a0 *= f; a1 *= f; a2 *= f; a3 *= f;
        #pragma unroll
        for (int t = 0; t < 4; t++) {
            a0 += p[t] * __half2float(__ushort_as_half(hh[t].x));
            a1 += p[t] * __half2float(__ushort_as_half(hh[t].y));
            a2 += p[t] * __half2float(__ushort_as_half(hh[t].z));
            a3 += p[t] * __half2float(__ushort_as_half(hh[t].w));
        }
    }
    for (; j < end; j++) {
        int s0 = csr_src[j];
        float e = al_s[s0 * 4 + h] + ald;
        e = (e >= 0.f) ? e : NEG * e;
        ushort4 hv = *(const ushort4*)(H1h + (size_t)s0 * C1 + lane * 4);
        float nm = fmaxf(m, e);
        float f  = __expf(m - nm);
        float pr = __expf(e - nm);
        s  = s  * f + pr;
        a0 = a0 * f + pr * __half2float(__ushort_as_half(hv.x));
        a1 = a1 * f + pr * __half2float(__ushort_as_half(hv.y));
        a2 = a2 * f + pr * __half2float(__ushort_as_half(hv.z));
        a3 = a3 * f + pr * __half2float(__ushort_as_half(hv.w));
        m = nm;
    }
    float inv = 1.f / (s + 1e-16f);
    float4 bb = *(const float4*)(b1 + lane * 4);
    float o0 = a0 * inv + bb.x, o1 = a1 * inv + bb.y;
    float o2 = a2 * inv + bb.z, o3 = a3 * inv + bb.w;
    o0 = (o0 > 0.f) ? o0 : expm1f(o0);
    o1 = (o1 > 0.f) ? o1 : expm1f(o1);
    o2 = (o2 > 0.f) ? o2 : expm1f(o2);
    o3 = (o3 > 0.f) ? o3 : expm1f(o3);
    ushort4 pk;
    pk.x = __half_as_ushort(__float2half_rn(o0));
    pk.y = __half_as_ushort(__float2half_rn(o1));
    pk.z = __half_as_ushort(__float2half_rn(o2));
    pk.w = __half_as_ushort(__float2half_rn(o3));
    *(ushort4*)(HEh + (size_t)n * C1 + lane * 4) = pk;
}

// ---------------- Layer 2: GEMM (HE @ W2) via MFMA + logits ----------------
// One wave per 16 output rows (3125 waves, ~3/SIMD). 24 mfma_f32_16x16x32_f16
// per wave. A-frag: lane holds HEh[n0+(lane&15)][ks*32+(lane>>4)*8 + 0..7].
// B-frags prepacked by k_prepw2f with the same k-mapping. D (m89-verified):
// col = lane&15, row = (lane>>4)*4 + reg.

__global__ void __launch_bounds__(64)
k_gemm2(const __half* __restrict__ HEh, const uint4* __restrict__ W2f,
        const float* __restrict__ a_src2, const float* __restrict__ a_dst2,
        __half* __restrict__ H2h, float* __restrict__ al_s2, float* __restrict__ al_d2) {
    int lane = threadIdx.x;
    int n0 = blockIdx.x * 16;
    const __half* aptr = HEh + (size_t)(n0 + (lane & 15)) * C1 + ((lane >> 4) << 3);
    const f16x8* bptr = (const f16x8*)W2f;
    f32x4 acc0 = {0.f, 0.f, 0.f, 0.f};
    f32x4 acc1 = {0.f, 0.f, 0.f, 0.f};
    f32x4 acc2 = {0.f, 0.f, 0.f, 0.f};
    #pragma unroll
    for (int ks = 0; ks < 8; ks++) {
        f16x8 a  = *(const f16x8*)(aptr + ks * 32);
        f16x8 b0 = bptr[(0 * 8 + ks) * 64 + lane];
        f16x8 b1 = bptr[(1 * 8 + ks) * 64 + lane];
        f16x8 b2 = bptr[(2 * 8 + ks) * 64 + lane];
        acc0 = __builtin_amdgcn_mfma_f32_16x16x32_f16(a, b0, acc0, 0, 0, 0);
        acc1 = __builtin_amdgcn_mfma_f32_16x16x32_f16(a, b1, acc1, 0, 0, 0);
        acc2 = __builtin_amdgcn_mfma_f32_16x16x32_f16(a, b2, acc2, 0, 0, 0);
    }
    int col = lane & 15;
    int g4  = (lane >> 4) * 4;
    float as[3], ad[3];
    #pragma unroll
    for (int f = 0; f < 3; f++) {
        int c = f * 16 + col;
        as[f] = (c < NCLS) ? a_src2[c] : 0.f;
        ad[f] = (c < NCLS) ? a_dst2[c] : 0.f;
    }
    #pragma unroll
    for (int reg = 0; reg < 4; reg++) {
        int n = n0 + g4 + reg;
        float v0 = acc0[reg], v1 = acc1[reg], v2 = acc2[reg];
        __half* orow = H2h + (size_t)n * H2S;
        orow[col]      = __float2half_rn(v0);
        orow[16 + col] = __float2half_rn(v1);
        orow[32 + col] = __float2half_rn(v2);   // col 47 = pad (zero from padded W2f)
        float vs = v0 * as[0] + v1 * as[1] + v2 * as[2];
        float vd = v0 * ad[0] + v1 * ad[1] + v2 * ad[2];
        #pragma unroll
        for (int off = 8; off; off >>= 1) {     // reduce across the 16-lane row group
            vs += __shfl_xor(vs, off);
            vd += __shfl_xor(vd, off);
        }
        if (col == 0) { al_s2[n] = vs; al_d2[n] = vd; }
    }
}

// ---------------- Layer 2 aggregation + bias + log_softmax ----------------
// one wave per node; lane<47 owns a class. 4-edge unroll (same structure as
// k_agg1) to break the serial per-edge latency chain.

__global__ void k_agg2(const __half* __restrict__ H2h, const float* __restrict__ al_s2,
                       const float* __restrict__ al_d2, const int* __restrict__ row_ptr,
                       const int* __restrict__ csr_src, const float* __restrict__ b2,
                       float* __restrict__ out) {
    int n = blockIdx.x * 4 + (threadIdx.x >> 6);
    if (n >= N_NODES) return;
    int lane = threadIdx.x & 63;
    int beg = row_ptr[n], end = row_ptr[n + 1];
    float ald = al_d2[n];
    float m = -INFINITY, s = 0.f, acc = 0.f;
    int j = beg;
    for (; j + 3 < end; j += 4) {
        int ss[4]; float ee[4]; float hv[4];
        #pragma unroll
        for (int t = 0; t < 4; t++) ss[t] = csr_src[j + t];
        #pragma unroll
        for (int t = 0; t < 4; t++) ee[t] = al_s2[ss[t]];
        #pragma unroll
        for (int t = 0; t < 4; t++)
            hv[t] = (lane < NCLS) ? __half2float(H2h[(size_t)ss[t] * H2S + lane]) : 0.f;
        #pragma unroll
        for (int t = 0; t < 4; t++) {
            float e = ee[t] + ald;
            ee[t] = (e >= 0.f) ? e : NEG * e;
        }
        float nm = fmaxf(m, fmaxf(fmaxf(ee[0], ee[1]), fmaxf(ee[2], ee[3])));
        float f = __expf(m - nm);
        m = nm;
        float p[4];
        #pragma unroll
        for (int t = 0; t < 4; t++) p[t] = __expf(ee[t] - nm);
        s = s * f + p[0] + p[1] + p[2] + p[3];
        acc = acc * f + p[0] * hv[0] + p[1] * hv[1] + p[2] * hv[2] + p[3] * hv[3];
    }
    for (; j < end; j++) {
        int src = csr_src[j];
        float e = al_s2[src] + ald;
        e = (e >= 0.f) ? e : NEG * e;
        float hv = (lane < NCLS) ? __half2float(H2h[(size_t)src * H2S + lane]) : 0.f;
        float nm = fmaxf(m, e);
        float f  = __expf(m - nm);
        float pr = __expf(e - nm);
        s   = s   * f + pr;
        acc = acc * f + pr * hv;
        m = nm;
    }
    float v = acc / (s + 1e-16f) + ((lane < NCLS) ? b2[lane] : -INFINITY);
    float mx = v;
    #pragma unroll
    for (int off = 32; off; off >>= 1) mx = fmaxf(mx, __shfl_xor(mx, off));
    float ex = __expf(v - mx);            // lanes >= 47 contribute 0
    float sum = ex;
    #pragma unroll
    for (int off = 32; off; off >>= 1) sum += __shfl_xor(sum, off);
    if (lane < NCLS) out[(size_t)n * NCLS + lane] = v - mx - logf(sum);
}

// ---------------- host ----------------

extern "C" void kernel_launch(void* const* d_in, const int* in_sizes, int n_in,
                              void* d_out, int out_size, void* d_ws, size_t ws_size,
                              hipStream_t stream) {
    const float* x      = (const float*)d_in[0];
    const int*   ei     = (const int*)  d_in[1];
    const float* W1     = (const float*)d_in[2];
    const float* a_src1 = (const float*)d_in[3];
    const float* a_dst1 = (const float*)d_in[4];
    const float* b1     = (const float*)d_in[5];
    const float* W2     = (const float*)d_in[6];
    const float* a_src2 = (const float*)d_in[7];
    const float* a_dst2 = (const float*)d_in[8];
    const float* b2     = (const float*)d_in[9];
    float* out = (float*)d_out;

    char* base = (char*)d_ws;
    size_t off = 0;
    auto alloc = [&](size_t bytes) -> void* {
        void* r = base + off;
        off += (bytes + 511) & ~size_t(511);
        return r;
    };
    __half* H1h   = (__half*)alloc((size_t)N_NODES * C1 * 2);
    __half* HEh   = (__half*)alloc((size_t)N_NODES * C1 * 2);
    __half* H2h   = (__half*)alloc((size_t)N_NODES * H2S * 2);
    uint4*  W2f   = (uint4*) alloc((size_t)1536 * 16);
    float*  al_s1 = (float*) alloc((size_t)N_NODES * 4 * 4);
    float*  al_d1 = (float*) alloc((size_t)N_NODES * 4 * 4);
    float*  al_s2 = (float*) alloc((size_t)N_NODES * 4);
    float*  al_d2 = (float*) alloc((size_t)N_NODES * 4);
    int*    deg   = (int*)   alloc((size_t)N_NODES * 4);
    int*    rowp  = (int*)   alloc((size_t)(N_NODES + 1) * 4);
    int*    cursor= (int*)   alloc((size_t)N_NODES * 4);
    int*    blks  = (int*)   alloc((size_t)SCAN_B * 4);
    int*    blko  = (int*)   alloc((size_t)SCAN_B * 4);
    int*    csrs  = (int*)   alloc((size_t)E_TOT * 4);

    hipMemsetAsync(deg, 0, (size_t)N_NODES * 4, stream);

    int eb = (E_TOT + 255) / 256;
    k_count   <<<eb, 256, 0, stream>>>(ei, deg);
    k_scan_blk<<<SCAN_B, 256, 0, stream>>>(deg, blks);
    k_scan_top<<<1, 256, 0, stream>>>(blks, blko);
    k_scan_fin<<<SCAN_B, 256, 0, stream>>>(deg, blko, rowp, cursor);
    k_scatter <<<eb, 256, 0, stream>>>(ei, cursor, csrs);
    k_prepw2f <<<6, 256, 0, stream>>>(W2, W2f);

    k_gemm1<<<N_NODES / 16, 64, 0, stream>>>(x, W1, a_src1, a_dst1, H1h, al_s1, al_d1);
    k_agg1 <<<(N_NODES + 3) / 4, 256, 0, stream>>>(H1h, al_s1, al_d1, rowp, csrs, b1, HEh);
    k_gemm2<<<N_NODES / 16, 64, 0, stream>>>(HEh, W2f, a_src2, a_dst2, H2h, al_s2, al_d2);
    k_agg2 <<<(N_NODES + 3) / 4, 256, 0, stream>>>(H2h, al_s2, al_d2, rowp, csrs, b2, out);
}

// Round 12
// 349.118 us; speedup vs baseline: 1.4507x; 1.1193x over previous
//
#include <hip/hip_runtime.h>
#include <hip/hip_fp16.h>
#include <math.h>

#define N_NODES 50000
#define E_EDGES 800000
#define E_TOT   850000   // E_EDGES + N_NODES self loops
#define F_IN    128
#define C1      256      // HEADS*HID
#define NCLS    47
#define H2S     48       // padded stride for H2 (47 -> 48)
#define NEG     0.2f
#define SCAN_B  196      // ceil(50000/256)

typedef _Float16 f16x8 __attribute__((ext_vector_type(8)));
typedef float    f32x4 __attribute__((ext_vector_type(4)));

// ---------------- CSR build ----------------

__global__ void k_count(const int* __restrict__ ei, int* __restrict__ deg) {
    int i = blockIdx.x * 256 + threadIdx.x;
    if (i >= E_TOT) return;
    int dst = (i < E_EDGES) ? ei[E_EDGES + i] : (i - E_EDGES);
    atomicAdd(&deg[dst], 1);
}

// pass 1: per-block sums of deg
__global__ void k_scan_blk(const int* __restrict__ deg, int* __restrict__ blksum) {
    __shared__ int ws[4];
    int i = blockIdx.x * 256 + threadIdx.x;
    int v = (i < N_NODES) ? deg[i] : 0;
    int lane = threadIdx.x & 63, w = threadIdx.x >> 6;
    #pragma unroll
    for (int off = 32; off; off >>= 1) v += __shfl_xor(v, off);
    if (lane == 0) ws[w] = v;
    __syncthreads();
    if (threadIdx.x == 0) blksum[blockIdx.x] = ws[0] + ws[1] + ws[2] + ws[3];
}

// pass 2: single block exclusive-scans the SCAN_B block sums
__global__ void k_scan_top(const int* __restrict__ blksum, int* __restrict__ blkoff) {
    __shared__ int ws[4];
    int tid = threadIdx.x, lane = tid & 63, w = tid >> 6;
    int v = (tid < SCAN_B) ? blksum[tid] : 0;
    int sc = v;
    #pragma unroll
    for (int off = 1; off < 64; off <<= 1) {
        int t = __shfl_up(sc, off);
        if (lane >= off) sc += t;
    }
    if (lane == 63) ws[w] = sc;
    __syncthreads();
    if (tid == 0) { int a = 0; for (int t = 0; t < 4; t++) { int u = ws[t]; ws[t] = a; a += u; } }
    __syncthreads();
    if (tid < SCAN_B) blkoff[tid] = sc + ws[w] - v;   // exclusive
}

// pass 3: local scan + block offset -> row_ptr / cursor
__global__ void k_scan_fin(const int* __restrict__ deg, const int* __restrict__ blkoff,
                           int* __restrict__ row_ptr, int* __restrict__ cursor) {
    __shared__ int ws[4];
    int i = blockIdx.x * 256 + threadIdx.x;
    int v = (i < N_NODES) ? deg[i] : 0;
    int lane = threadIdx.x & 63, w = threadIdx.x >> 6;
    int sc = v;
    #pragma unroll
    for (int off = 1; off < 64; off <<= 1) {
        int t = __shfl_up(sc, off);
        if (lane >= off) sc += t;
    }
    if (lane == 63) ws[w] = sc;
    __syncthreads();
    if (threadIdx.x == 0) { int a = 0; for (int t = 0; t < 4; t++) { int u = ws[t]; ws[t] = a; a += u; } }
    __syncthreads();
    int incl = sc + ws[w] + blkoff[blockIdx.x];
    if (i < N_NODES) {
        row_ptr[i + 1] = incl;
        cursor[i]      = incl - v;
    }
    if (i == 0) row_ptr[0] = 0;
}

__global__ void k_scatter(const int* __restrict__ ei, int* __restrict__ cursor,
                          int* __restrict__ csr_src) {
    int i = blockIdx.x * 256 + threadIdx.x;
    if (i >= E_TOT) return;
    int src, dst;
    if (i < E_EDGES) { src = ei[i]; dst = ei[E_EDGES + i]; }
    else             { src = dst = i - E_EDGES; }
    int pos = atomicAdd(&cursor[dst], 1);
    csr_src[pos] = src;
}

// ---------------- x -> fp16 convert (gemm1 MFMA A-operand) ----------------

__global__ void k_prepx(const float* __restrict__ x, __half* __restrict__ xh) {
    int i = blockIdx.x * 256 + threadIdx.x;        // float4 units
    if (i >= N_NODES * F_IN / 4) return;
    float4 v = ((const float4*)x)[i];
    ushort4 p;
    p.x = __half_as_ushort(__float2half_rn(v.x));
    p.y = __half_as_ushort(__float2half_rn(v.y));
    p.z = __half_as_ushort(__float2half_rn(v.z));
    p.w = __half_as_ushort(__float2half_rn(v.w));
    ((ushort4*)xh)[i] = p;
}

// ---------------- W1 prep: pack into MFMA B-fragments (fp16) ----------------
// W1f[(f*4+ks)*64 + lane] = 8 halves: W1[k = ks*32 + (lane>>4)*8 + j][c = f*16 + (lane&15)].
// Same k-mapping as the A-frag load in k_gemm1, so any k-order bijection cancels.

__global__ void k_prepw1f(const float* __restrict__ W1, uint4* __restrict__ W1f) {
    int t = blockIdx.x * 256 + threadIdx.x;
    if (t >= 4096) return;                          // 16 f * 4 ks * 64 lanes
    int f = t >> 8, ks = (t >> 6) & 3, lane = t & 63;
    int c  = f * 16 + (lane & 15);
    int kb = ks * 32 + ((lane >> 4) << 3);
    unsigned short h[8];
    #pragma unroll
    for (int j = 0; j < 8; j++)
        h[j] = __half_as_ushort(__float2half_rn(W1[(size_t)(kb + j) * C1 + c]));
    W1f[t] = make_uint4((unsigned)h[0] | ((unsigned)h[1] << 16),
                        (unsigned)h[2] | ((unsigned)h[3] << 16),
                        (unsigned)h[4] | ((unsigned)h[5] << 16),
                        (unsigned)h[6] | ((unsigned)h[7] << 16));
}

// ---------------- W2 prep: pack into MFMA B-fragments (fp16) ----------------

__global__ void k_prepw2f(const float* __restrict__ W2, uint4* __restrict__ W2f) {
    int t = blockIdx.x * 256 + threadIdx.x;
    if (t >= 1536) return;
    int f = t >> 9, ks = (t >> 6) & 7, lane = t & 63;
    int c  = f * 16 + (lane & 15);
    int kb = ks * 32 + ((lane >> 4) << 3);
    unsigned short h[8];
    #pragma unroll
    for (int j = 0; j < 8; j++) {
        float v = (c < NCLS) ? W2[(size_t)(kb + j) * NCLS + c] : 0.f;
        h[j] = __half_as_ushort(__float2half_rn(v));
    }
    W2f[t] = make_uint4((unsigned)h[0] | ((unsigned)h[1] << 16),
                        (unsigned)h[2] | ((unsigned)h[3] << 16),
                        (unsigned)h[4] | ((unsigned)h[5] << 16),
                        (unsigned)h[6] | ((unsigned)h[7] << 16));
}

// ---------------- Layer 1: GEMM (x @ W1) via MFMA + attention logits ----------
// One wave per 16 rows (3125 waves). 64 mfma_f32_16x16x32_f16 per wave
// (4 ks-steps x 16 col-tiles). A-frag: lane holds xh[n0+(lane&15)][ks*32+(lane>>4)*8+0..7].
// D (m89-verified, proven in k_gemm2): col = f*16 + (lane&15), row = (lane>>4)*4 + reg.
// Logits from fp32 accumulators: per-head partial sums, 16-lane-group reduce.

__global__ void __launch_bounds__(64)
k_gemm1(const __half* __restrict__ xh, const uint4* __restrict__ W1f,
        const float* __restrict__ a_src1, const float* __restrict__ a_dst1,
        __half* __restrict__ H1h, float* __restrict__ al_s, float* __restrict__ al_d) {
    int lane = threadIdx.x;
    int n0 = blockIdx.x * 16;
    const __half* aptr = xh + (size_t)(n0 + (lane & 15)) * F_IN + ((lane >> 4) << 3);
    const f16x8* bptr = (const f16x8*)W1f;
    f32x4 acc[16];
    #pragma unroll
    for (int f = 0; f < 16; f++) acc[f] = (f32x4){0.f, 0.f, 0.f, 0.f};
    #pragma unroll
    for (int ks = 0; ks < 4; ks++) {
        f16x8 a = *(const f16x8*)(aptr + ks * 32);
        #pragma unroll
        for (int f = 0; f < 16; f++) {
            f16x8 b = bptr[(f * 4 + ks) * 64 + lane];
            acc[f] = __builtin_amdgcn_mfma_f32_16x16x32_f16(a, b, acc[f], 0, 0, 0);
        }
    }
    int col = lane & 15;
    int g4  = (lane >> 4) * 4;
    float asf[16], adf[16];
    #pragma unroll
    for (int f = 0; f < 16; f++) {                  // flat c index == h*64 + cc
        asf[f] = a_src1[f * 16 + col];
        adf[f] = a_dst1[f * 16 + col];
    }
    #pragma unroll
    for (int reg = 0; reg < 4; reg++) {
        int n = n0 + g4 + reg;
        float vs[4] = {0.f, 0.f, 0.f, 0.f};
        float vd[4] = {0.f, 0.f, 0.f, 0.f};
        #pragma unroll
        for (int f = 0; f < 16; f++) {
            float v = acc[f][reg];
            H1h[(size_t)n * C1 + f * 16 + col] = __float2half_rn(v);
            vs[f >> 2] += v * asf[f];
            vd[f >> 2] += v * adf[f];
        }
        #pragma unroll
        for (int h = 0; h < 4; h++) {
            #pragma unroll
            for (int off = 8; off; off >>= 1) {     // reduce within 16-lane col group
                vs[h] += __shfl_xor(vs[h], off);
                vd[h] += __shfl_xor(vd[h], off);
            }
        }
        if (col == 0) {
            #pragma unroll
            for (int h = 0; h < 4; h++) {
                al_s[n * 4 + h] = vs[h];
                al_d[n * 4 + h] = vd[h];
            }
        }
    }
}

// ---------------- Layer 1 aggregation: online softmax, one wave per node ----------------
// fp16 rows (512B), 4-edge unroll. Output HE fp16 (feeds gemm2's MFMA A-operand).

__global__ void k_agg1(const __half* __restrict__ H1h, const float* __restrict__ al_s,
                       const float* __restrict__ al_d, const int* __restrict__ row_ptr,
                       const int* __restrict__ csr_src, const float* __restrict__ b1,
                       __half* __restrict__ HEh) {
    int n = blockIdx.x * 4 + (threadIdx.x >> 6);
    int lane = threadIdx.x & 63;
    int h = lane >> 4;
    int beg = row_ptr[n], end = row_ptr[n + 1];
    float ald = al_d[n * 4 + h];
    float m = -INFINITY, s = 0.f;
    float a0 = 0.f, a1 = 0.f, a2 = 0.f, a3 = 0.f;
    int j = beg;
    for (; j + 3 < end; j += 4) {
        int ss[4]; float ee[4]; ushort4 hh[4];
        #pragma unroll
        for (int t = 0; t < 4; t++) ss[t] = csr_src[j + t];
        #pragma unroll
        for (int t = 0; t < 4; t++) ee[t] = al_s[ss[t] * 4 + h];
        #pragma unroll
        for (int t = 0; t < 4; t++)
            hh[t] = *(const ushort4*)(H1h + (size_t)ss[t] * C1 + lane * 4);
        #pragma unroll
        for (int t = 0; t < 4; t++) {
            float e = ee[t] + ald;
            ee[t] = (e >= 0.f) ? e : NEG * e;
        }
        float nm = fmaxf(m, fmaxf(fmaxf(ee[0], ee[1]), fmaxf(ee[2], ee[3])));
        float f = __expf(m - nm);
        m = nm;
        float p[4];
        #pragma unroll
        for (int t = 0; t < 4; t++) p[t] = __expf(ee[t] - nm);
        s = s * f + p[0] + p[1] + p[2] + p[3];
        a0 *= f; a1 *= f; a2 *= f; a3 *= f;
        #pragma unroll
        for (int t = 0; t < 4; t++) {
            a0 += p[t] * __half2float(__ushort_as_half(hh[t].x));
            a1 += p[t] * __half2float(__ushort_as_half(hh[t].y));
            a2 += p[t] * __half2float(__ushort_as_half(hh[t].z));
            a3 += p[t] * __half2float(__ushort_as_half(hh[t].w));
        }
    }
    for (; j < end; j++) {
        int s0 = csr_src[j];
        float e = al_s[s0 * 4 + h] + ald;
        e = (e >= 0.f) ? e : NEG * e;
        ushort4 hv = *(const ushort4*)(H1h + (size_t)s0 * C1 + lane * 4);
        float nm = fmaxf(m, e);
        float f  = __expf(m - nm);
        float pr = __expf(e - nm);
        s  = s  * f + pr;
        a0 = a0 * f + pr * __half2float(__ushort_as_half(hv.x));
        a1 = a1 * f + pr * __half2float(__ushort_as_half(hv.y));
        a2 = a2 * f + pr * __half2float(__ushort_as_half(hv.z));
        a3 = a3 * f + pr * __half2float(__ushort_as_half(hv.w));
        m = nm;
    }
    float inv = 1.f / (s + 1e-16f);
    float4 bb = *(const float4*)(b1 + lane * 4);
    float o0 = a0 * inv + bb.x, o1 = a1 * inv + bb.y;
    float o2 = a2 * inv + bb.z, o3 = a3 * inv + bb.w;
    o0 = (o0 > 0.f) ? o0 : expm1f(o0);
    o1 = (o1 > 0.f) ? o1 : expm1f(o1);
    o2 = (o2 > 0.f) ? o2 : expm1f(o2);
    o3 = (o3 > 0.f) ? o3 : expm1f(o3);
    ushort4 pk;
    pk.x = __half_as_ushort(__float2half_rn(o0));
    pk.y = __half_as_ushort(__float2half_rn(o1));
    pk.z = __half_as_ushort(__float2half_rn(o2));
    pk.w = __half_as_ushort(__float2half_rn(o3));
    *(ushort4*)(HEh + (size_t)n * C1 + lane * 4) = pk;
}

// ---------------- Layer 2: GEMM (HE @ W2) via MFMA + logits ----------------

__global__ void __launch_bounds__(64)
k_gemm2(const __half* __restrict__ HEh, const uint4* __restrict__ W2f,
        const float* __restrict__ a_src2, const float* __restrict__ a_dst2,
        __half* __restrict__ H2h, float* __restrict__ al_s2, float* __restrict__ al_d2) {
    int lane = threadIdx.x;
    int n0 = blockIdx.x * 16;
    const __half* aptr = HEh + (size_t)(n0 + (lane & 15)) * C1 + ((lane >> 4) << 3);
    const f16x8* bptr = (const f16x8*)W2f;
    f32x4 acc0 = {0.f, 0.f, 0.f, 0.f};
    f32x4 acc1 = {0.f, 0.f, 0.f, 0.f};
    f32x4 acc2 = {0.f, 0.f, 0.f, 0.f};
    #pragma unroll
    for (int ks = 0; ks < 8; ks++) {
        f16x8 a  = *(const f16x8*)(aptr + ks * 32);
        f16x8 b0 = bptr[(0 * 8 + ks) * 64 + lane];
        f16x8 b1 = bptr[(1 * 8 + ks) * 64 + lane];
        f16x8 b2 = bptr[(2 * 8 + ks) * 64 + lane];
        acc0 = __builtin_amdgcn_mfma_f32_16x16x32_f16(a, b0, acc0, 0, 0, 0);
        acc1 = __builtin_amdgcn_mfma_f32_16x16x32_f16(a, b1, acc1, 0, 0, 0);
        acc2 = __builtin_amdgcn_mfma_f32_16x16x32_f16(a, b2, acc2, 0, 0, 0);
    }
    int col = lane & 15;
    int g4  = (lane >> 4) * 4;
    float as[3], ad[3];
    #pragma unroll
    for (int f = 0; f < 3; f++) {
        int c = f * 16 + col;
        as[f] = (c < NCLS) ? a_src2[c] : 0.f;
        ad[f] = (c < NCLS) ? a_dst2[c] : 0.f;
    }
    #pragma unroll
    for (int reg = 0; reg < 4; reg++) {
        int n = n0 + g4 + reg;
        float v0 = acc0[reg], v1 = acc1[reg], v2 = acc2[reg];
        __half* orow = H2h + (size_t)n * H2S;
        orow[col]      = __float2half_rn(v0);
        orow[16 + col] = __float2half_rn(v1);
        orow[32 + col] = __float2half_rn(v2);   // col 47 = pad (zero from padded W2f)
        float vs = v0 * as[0] + v1 * as[1] + v2 * as[2];
        float vd = v0 * ad[0] + v1 * ad[1] + v2 * ad[2];
        #pragma unroll
        for (int off = 8; off; off >>= 1) {     // reduce across the 16-lane row group
            vs += __shfl_xor(vs, off);
            vd += __shfl_xor(vd, off);
        }
        if (col == 0) { al_s2[n] = vs; al_d2[n] = vd; }
    }
}

// ---------------- Layer 2 aggregation + bias + log_softmax ----------------
// one wave per node; lane<47 owns a class. 4-edge unroll.

__global__ void k_agg2(const __half* __restrict__ H2h, const float* __restrict__ al_s2,
                       const float* __restrict__ al_d2, const int* __restrict__ row_ptr,
                       const int* __restrict__ csr_src, const float* __restrict__ b2,
                       float* __restrict__ out) {
    int n = blockIdx.x * 4 + (threadIdx.x >> 6);
    if (n >= N_NODES) return;
    int lane = threadIdx.x & 63;
    int beg = row_ptr[n], end = row_ptr[n + 1];
    float ald = al_d2[n];
    float m = -INFINITY, s = 0.f, acc = 0.f;
    int j = beg;
    for (; j + 3 < end; j += 4) {
        int ss[4]; float ee[4]; float hv[4];
        #pragma unroll
        for (int t = 0; t < 4; t++) ss[t] = csr_src[j + t];
        #pragma unroll
        for (int t = 0; t < 4; t++) ee[t] = al_s2[ss[t]];
        #pragma unroll
        for (int t = 0; t < 4; t++)
            hv[t] = (lane < NCLS) ? __half2float(H2h[(size_t)ss[t] * H2S + lane]) : 0.f;
        #pragma unroll
        for (int t = 0; t < 4; t++) {
            float e = ee[t] + ald;
            ee[t] = (e >= 0.f) ? e : NEG * e;
        }
        float nm = fmaxf(m, fmaxf(fmaxf(ee[0], ee[1]), fmaxf(ee[2], ee[3])));
        float f = __expf(m - nm);
        m = nm;
        float p[4];
        #pragma unroll
        for (int t = 0; t < 4; t++) p[t] = __expf(ee[t] - nm);
        s = s * f + p[0] + p[1] + p[2] + p[3];
        acc = acc * f + p[0] * hv[0] + p[1] * hv[1] + p[2] * hv[2] + p[3] * hv[3];
    }
    for (; j < end; j++) {
        int src = csr_src[j];
        float e = al_s2[src] + ald;
        e = (e >= 0.f) ? e : NEG * e;
        float hv = (lane < NCLS) ? __half2float(H2h[(size_t)src * H2S + lane]) : 0.f;
        float nm = fmaxf(m, e);
        float f  = __expf(m - nm);
        float pr = __expf(e - nm);
        s   = s   * f + pr;
        acc = acc * f + pr * hv;
        m = nm;
    }
    float v = acc / (s + 1e-16f) + ((lane < NCLS) ? b2[lane] : -INFINITY);
    float mx = v;
    #pragma unroll
    for (int off = 32; off; off >>= 1) mx = fmaxf(mx, __shfl_xor(mx, off));
    float ex = __expf(v - mx);            // lanes >= 47 contribute 0
    float sum = ex;
    #pragma unroll
    for (int off = 32; off; off >>= 1) sum += __shfl_xor(sum, off);
    if (lane < NCLS) out[(size_t)n * NCLS + lane] = v - mx - logf(sum);
}

// ---------------- host ----------------

extern "C" void kernel_launch(void* const* d_in, const int* in_sizes, int n_in,
                              void* d_out, int out_size, void* d_ws, size_t ws_size,
                              hipStream_t stream) {
    const float* x      = (const float*)d_in[0];
    const int*   ei     = (const int*)  d_in[1];
    const float* W1     = (const float*)d_in[2];
    const float* a_src1 = (const float*)d_in[3];
    const float* a_dst1 = (const float*)d_in[4];
    const float* b1     = (const float*)d_in[5];
    const float* W2     = (const float*)d_in[6];
    const float* a_src2 = (const float*)d_in[7];
    const float* a_dst2 = (const float*)d_in[8];
    const float* b2     = (const float*)d_in[9];
    float* out = (float*)d_out;

    char* base = (char*)d_ws;
    size_t off = 0;
    auto alloc = [&](size_t bytes) -> void* {
        void* r = base + off;
        off += (bytes + 511) & ~size_t(511);
        return r;
    };
    __half* H1h   = (__half*)alloc((size_t)N_NODES * C1 * 2);
    __half* HEh   = (__half*)alloc((size_t)N_NODES * C1 * 2);
    __half* H2h   = (__half*)alloc((size_t)N_NODES * H2S * 2);
    __half* xh    = (__half*)alloc((size_t)N_NODES * F_IN * 2);
    uint4*  W1f   = (uint4*) alloc((size_t)4096 * 16);
    uint4*  W2f   = (uint4*) alloc((size_t)1536 * 16);
    float*  al_s1 = (float*) alloc((size_t)N_NODES * 4 * 4);
    float*  al_d1 = (float*) alloc((size_t)N_NODES * 4 * 4);
    float*  al_s2 = (float*) alloc((size_t)N_NODES * 4);
    float*  al_d2 = (float*) alloc((size_t)N_NODES * 4);
    int*    deg   = (int*)   alloc((size_t)N_NODES * 4);
    int*    rowp  = (int*)   alloc((size_t)(N_NODES + 1) * 4);
    int*    cursor= (int*)   alloc((size_t)N_NODES * 4);
    int*    blks  = (int*)   alloc((size_t)SCAN_B * 4);
    int*    blko  = (int*)   alloc((size_t)SCAN_B * 4);
    int*    csrs  = (int*)   alloc((size_t)E_TOT * 4);

    hipMemsetAsync(deg, 0, (size_t)N_NODES * 4, stream);

    int eb = (E_TOT + 255) / 256;
    k_count   <<<eb, 256, 0, stream>>>(ei, deg);
    k_scan_blk<<<SCAN_B, 256, 0, stream>>>(deg, blks);
    k_scan_top<<<1, 256, 0, stream>>>(blks, blko);
    k_scan_fin<<<SCAN_B, 256, 0, stream>>>(deg, blko, rowp, cursor);
    k_scatter <<<eb, 256, 0, stream>>>(ei, cursor, csrs);
    k_prepx   <<<(N_NODES * F_IN / 4 + 255) / 256, 256, 0, stream>>>(x, xh);
    k_prepw1f <<<16, 256, 0, stream>>>(W1, W1f);
    k_prepw2f <<<6, 256, 0, stream>>>(W2, W2f);

    k_gemm1<<<N_NODES / 16, 64, 0, stream>>>(xh, W1f, a_src1, a_dst1, H1h, al_s1, al_d1);
    k_agg1 <<<(N_NODES + 3) / 4, 256, 0, stream>>>(H1h, al_s1, al_d1, rowp, csrs, b1, HEh);
    k_gemm2<<<N_NODES / 16, 64, 0, stream>>>(HEh, W2f, a_src2, a_dst2, H2h, al_s2, al_d2);
    k_agg2 <<<(N_NODES + 3) / 4, 256, 0, stream>>>(H2h, al_s2, al_d2, rowp, csrs, b2, out);
}